// Round 1
// baseline (2997.840 us; speedup 1.0000x reference)
//
#include <hip/hip_runtime.h>

#define NN 20000
#define NE 640000
#define NCH 8      // K=4 eigenvectors x {+,-} sign
#define HID 64
#define EDIM 32
#define ODIM 64

// ---------------- layer 0: edge message + scatter (in_dim = 1) ----------------
__global__ __launch_bounds__(256) void k_l0_edge(
    const float* __restrict__ ea, const int* __restrict__ ei,
    const float* __restrict__ x, const float* __restrict__ We,
    const float* __restrict__ be, float* __restrict__ agg0)
{
    __shared__ float sWe[EDIM];
    __shared__ float sbe;
    if (threadIdx.x < EDIM) sWe[threadIdx.x] = We[threadIdx.x];
    if (threadIdx.x == 0) sbe = be[0];
    __syncthreads();
    int e = blockIdx.x * 256 + threadIdx.x;
    if (e >= NE) return;
    int s = ei[e];
    int d = ei[NE + e];
    const float* row = ea + (size_t)e * EDIM;
    float e0 = sbe;
#pragma unroll
    for (int dd = 0; dd < EDIM; ++dd) e0 = fmaf(row[dd], sWe[dd], e0);
#pragma unroll
    for (int k = 0; k < 4; ++k) {
        float xv = x[k * NN + s];
        atomicAdd(&agg0[k * NN + d], fmaxf(xv + e0, 0.f));
        atomicAdd(&agg0[(k + 4) * NN + d], fmaxf(-xv + e0, 0.f));
    }
}

// ---------------- layer 0: node MLP (scalar z -> 64 -> 64), inter-layer relu ----------------
__global__ __launch_bounds__(256) void k_l0_node(
    const float* __restrict__ x, const float* __restrict__ agg0,
    const float* __restrict__ W1, const float* __restrict__ b1,
    const float* __restrict__ W2, const float* __restrict__ b2,
    float* __restrict__ h)
{
    int lane = threadIdx.x & 63;
    float w1l = W1[lane];   // W1 is (1, HID)
    float b1l = b1[lane];
    float b2l = b2[lane];
    float w2c[HID];
#pragma unroll
    for (int j = 0; j < HID; ++j) w2c[j] = W2[j * HID + lane];
    int wid = (blockIdx.x * 256 + threadIdx.x) >> 6;
    int nw = (gridDim.x * 256) >> 6;
    for (int t = wid; t < NCH * NN; t += nw) {
        int c = t / NN;
        int n = t - c * NN;
        float xv = x[(c & 3) * NN + n];
        if (c >= 4) xv = -xv;
        float z = xv + agg0[t];                   // z = h + agg (EPS=0)
        float tt = fmaxf(fmaf(z, w1l, b1l), 0.f); // relu(z@W1+b1), lane = hidden idx
        float acc = b2l;
#pragma unroll
        for (int j = 0; j < HID; ++j) acc = fmaf(__shfl(tt, j, 64), w2c[j], acc);
        h[(size_t)t * HID + lane] = fmaxf(acc, 0.f);  // inter-layer relu
    }
}

// ---------------- layers 1/2: edge embed (on the fly) + message + scatter ----------------
__global__ __launch_bounds__(256) void k_edge(
    const float* __restrict__ ea, const int* __restrict__ ei,
    const float* __restrict__ We, const float* __restrict__ be,
    const float* __restrict__ h, float* __restrict__ agg)
{
    int lane = threadIdx.x & 63;
    float wcol[EDIM];
#pragma unroll
    for (int dd = 0; dd < EDIM; ++dd) wcol[dd] = We[dd * HID + lane]; // coalesced per dd
    float bel = be[lane];
    int wid = (blockIdx.x * 256 + threadIdx.x) >> 6;
    int nw = (gridDim.x * 256) >> 6;
    for (int e = wid; e < NE; e += nw) {
        int s = ei[e];
        int d = ei[NE + e];
        float r = (lane < EDIM) ? ea[(size_t)e * EDIM + lane] : 0.f; // 128B coalesced
        float em = bel;
#pragma unroll
        for (int dd = 0; dd < EDIM; ++dd) em = fmaf(__shfl(r, dd, 64), wcol[dd], em);
        const float* hs = h + (size_t)s * HID + lane;
        float* ad = agg + (size_t)d * HID + lane;
#pragma unroll
        for (int c = 0; c < NCH; ++c) {
            float v = fmaxf(hs[(size_t)c * NN * HID] + em, 0.f);
            atomicAdd(&ad[(size_t)c * NN * HID], v);
        }
    }
}

// ---------------- layers 1/2: node MLP 64 -> 64 -> OUT ----------------
template <int OUT, bool DORELU>
__global__ __launch_bounds__(256) void k_node(
    const float* __restrict__ h, const float* __restrict__ agg,
    const float* __restrict__ W1, const float* __restrict__ b1,
    const float* __restrict__ W2, const float* __restrict__ b2,
    float* __restrict__ out)
{
    int lane = threadIdx.x & 63;
    float w1c[HID], w2c[HID];
#pragma unroll
    for (int j = 0; j < HID; ++j) w1c[j] = W1[j * HID + lane];
#pragma unroll
    for (int j = 0; j < HID; ++j) w2c[j] = (lane < OUT) ? W2[j * OUT + lane] : 0.f;
    float b1l = b1[lane];
    float b2l = (lane < OUT) ? b2[lane] : 0.f;
    int wid = (blockIdx.x * 256 + threadIdx.x) >> 6;
    int nw = (gridDim.x * 256) >> 6;
    for (int t = wid; t < NCH * NN; t += nw) {
        float z = h[(size_t)t * HID + lane] + agg[(size_t)t * HID + lane];
        float acc = b1l;
#pragma unroll
        for (int j = 0; j < HID; ++j) acc = fmaf(__shfl(z, j, 64), w1c[j], acc);
        float tt = fmaxf(acc, 0.f);
        float acc2 = b2l;
#pragma unroll
        for (int j = 0; j < HID; ++j) acc2 = fmaf(__shfl(tt, j, 64), w2c[j], acc2);
        if (lane < OUT) out[(size_t)t * OUT + lane] = DORELU ? fmaxf(acc2, 0.f) : acc2;
    }
}

// ---------------- channel-sum pool + rho MLP 32 -> 64 -> 64 ----------------
__global__ __launch_bounds__(256) void k_rho(
    const float* __restrict__ h2,
    const float* __restrict__ Wr1, const float* __restrict__ br1,
    const float* __restrict__ Wr2, const float* __restrict__ br2,
    float* __restrict__ out)
{
    int lane = threadIdx.x & 63;
    float w1c[EDIM], w2c[HID];
#pragma unroll
    for (int j = 0; j < EDIM; ++j) w1c[j] = Wr1[j * HID + lane];
#pragma unroll
    for (int j = 0; j < HID; ++j) w2c[j] = Wr2[j * ODIM + lane];
    float b1l = br1[lane];
    float b2l = br2[lane];
    int wid = (blockIdx.x * 256 + threadIdx.x) >> 6;
    int nw = (gridDim.x * 256) >> 6;
    for (int n = wid; n < NN; n += nw) {
        float p = 0.f;
        if (lane < EDIM) {
#pragma unroll
            for (int c = 0; c < NCH; ++c) p += h2[((size_t)c * NN + n) * EDIM + lane];
        }
        float acc = b1l;
#pragma unroll
        for (int j = 0; j < EDIM; ++j) acc = fmaf(__shfl(p, j, 64), w1c[j], acc);
        float tt = fmaxf(acc, 0.f);
        float acc2 = b2l;
#pragma unroll
        for (int j = 0; j < HID; ++j) acc2 = fmaf(__shfl(tt, j, 64), w2c[j], acc2);
        out[(size_t)n * ODIM + lane] = acc2;
    }
}

extern "C" void kernel_launch(void* const* d_in, const int* in_sizes, int n_in,
                              void* d_out, int out_size, void* d_ws, size_t ws_size,
                              hipStream_t stream)
{
    const float* x   = (const float*)d_in[0];
    const float* ea  = (const float*)d_in[1];
    const int*   ei  = (const int*)d_in[2];
    const float* We0 = (const float*)d_in[3];
    const float* be0 = (const float*)d_in[4];
    const float* W10 = (const float*)d_in[5];
    const float* b10 = (const float*)d_in[6];
    const float* W20 = (const float*)d_in[7];
    const float* b20 = (const float*)d_in[8];
    const float* We1 = (const float*)d_in[9];
    const float* be1 = (const float*)d_in[10];
    const float* W11 = (const float*)d_in[11];
    const float* b11 = (const float*)d_in[12];
    const float* W21 = (const float*)d_in[13];
    const float* b21 = (const float*)d_in[14];
    const float* We2 = (const float*)d_in[15];
    const float* be2 = (const float*)d_in[16];
    const float* W12 = (const float*)d_in[17];
    const float* b12 = (const float*)d_in[18];
    const float* W22 = (const float*)d_in[19];
    const float* b22 = (const float*)d_in[20];
    const float* Wr1 = (const float*)d_in[21];
    const float* br1 = (const float*)d_in[22];
    const float* Wr2 = (const float*)d_in[23];
    const float* br2 = (const float*)d_in[24];
    float* out = (float*)d_out;

    // workspace layout (floats): h[8*N*64] | agg[8*N*64] | h2[8*N*32] | agg0[8*N]
    float* h    = (float*)d_ws;
    float* agg  = h + (size_t)NCH * NN * HID;
    float* h2   = agg + (size_t)NCH * NN * HID;
    float* agg0 = h2 + (size_t)NCH * NN * EDIM;

    // ---- layer 0 ----
    hipMemsetAsync(agg0, 0, (size_t)NCH * NN * sizeof(float), stream);
    k_l0_edge<<<NE / 256, 256, 0, stream>>>(ea, ei, x, We0, be0, agg0);
    k_l0_node<<<1024, 256, 0, stream>>>(x, agg0, W10, b10, W20, b20, h);

    // ---- layer 1 ----
    hipMemsetAsync(agg, 0, (size_t)NCH * NN * HID * sizeof(float), stream);
    k_edge<<<4096, 256, 0, stream>>>(ea, ei, We1, be1, h, agg);
    k_node<HID, true><<<1024, 256, 0, stream>>>(h, agg, W11, b11, W21, b21, h);

    // ---- layer 2 ----
    hipMemsetAsync(agg, 0, (size_t)NCH * NN * HID * sizeof(float), stream);
    k_edge<<<4096, 256, 0, stream>>>(ea, ei, We2, be2, h, agg);
    k_node<EDIM, false><<<1024, 256, 0, stream>>>(h, agg, W12, b12, W22, b22, h2);

    // ---- pool over channels + rho ----
    k_rho<<<256, 256, 0, stream>>>(h2, Wr1, br1, Wr2, br2, out);
}

// Round 2
// 1412.452 us; speedup vs baseline: 2.1224x; 2.1224x over previous
//
#include <hip/hip_runtime.h>

#define NN 20000
#define NE 640000
#define NCH 8      // K=4 eigenvectors x {+,-} sign
#define HID 64
#define EDIM 32
#define ODIM 64

// ---------------- CSR build: histogram ----------------
__global__ __launch_bounds__(256) void k_hist(const int* __restrict__ ei, int* __restrict__ cnt)
{
    int e = blockIdx.x * 256 + threadIdx.x;
    if (e < NE) atomicAdd(&cnt[ei[NE + e]], 1);
}

// ---------------- CSR build: single-block scan over 20000 counts ----------------
__global__ __launch_bounds__(512) void k_scan(const int* __restrict__ cnt,
                                              int* __restrict__ row, int* __restrict__ cursor)
{
    __shared__ int part[512];
    int t = threadIdx.x;
    int base = t * 40;                 // 512*40 = 20480 >= 20000
    int s = 0;
#pragma unroll
    for (int i = 0; i < 40; ++i) { int idx = base + i; if (idx < NN) s += cnt[idx]; }
    part[t] = s;
    __syncthreads();
    int v = s;
    for (int off = 1; off < 512; off <<= 1) {
        int add = (t >= off) ? part[t - off] : 0;
        __syncthreads();
        v += add;
        part[t] = v;
        __syncthreads();
    }
    int run = v - s;                   // exclusive prefix for this chunk
    for (int i = 0; i < 40; ++i) {
        int idx = base + i;
        if (idx < NN) { row[idx] = run; cursor[idx] = run; run += cnt[idx]; }
    }
    if (t == 511) row[NN] = NE;
}

// ---------------- CSR build: scatter (src, eid) into dst-grouped order ----------------
__global__ __launch_bounds__(256) void k_scatter(const int* __restrict__ ei,
                                                 int* __restrict__ cursor, int2* __restrict__ se)
{
    int e = blockIdx.x * 256 + threadIdx.x;
    if (e < NE) {
        int d = ei[NE + e];
        int pos = atomicAdd(&cursor[d], 1);
        se[pos] = make_int2(ei[e], e);
    }
}

// ---------------- layer 0 fused: gather edges (scalar feats) + node MLP ----------------
__global__ __launch_bounds__(256) void k_layer0(
    const float* __restrict__ x, const float* __restrict__ ea,
    const int2* __restrict__ se, const int* __restrict__ row,
    const float* __restrict__ We, const float* __restrict__ be,
    const float* __restrict__ W1, const float* __restrict__ b1,
    const float* __restrict__ W2, const float* __restrict__ b2,
    float* __restrict__ hout)
{
    int lane = threadIdx.x & 63;
    float we0 = (lane < EDIM) ? We[lane] : 0.f;   // We is (EDIM,1)
    float be0 = be[0];
    float w1l = W1[lane];                          // W1 is (1,HID)
    float b1l = b1[lane];
    float b2l = b2[lane];
    float w2c[HID];
#pragma unroll
    for (int j = 0; j < HID; ++j) w2c[j] = W2[j * HID + lane];

    int d = (blockIdx.x * 256 + threadIdx.x) >> 6;
    if (d >= NN) return;

    float acc[NCH];
#pragma unroll
    for (int c = 0; c < NCH; ++c) acc[c] = 0.f;

    int p1 = row[d + 1];
    for (int p = row[d]; p < p1; ++p) {
        int2 sp = se[p];
        float r = (lane < EDIM) ? ea[(size_t)sp.y * EDIM + lane] * we0 : 0.f;
        r += __shfl_xor(r, 16, 64);
        r += __shfl_xor(r, 8, 64);
        r += __shfl_xor(r, 4, 64);
        r += __shfl_xor(r, 2, 64);
        r += __shfl_xor(r, 1, 64);
        float e0 = __shfl(r, 0, 64) + be0;
#pragma unroll
        for (int k = 0; k < 4; ++k) {
            float xv = x[k * NN + sp.x];
            acc[k]     += fmaxf(xv + e0, 0.f);
            acc[k + 4] += fmaxf(-xv + e0, 0.f);
        }
    }

#pragma unroll
    for (int c = 0; c < NCH; ++c) {
        float xd = x[(c & 3) * NN + d];
        if (c >= 4) xd = -xd;
        float z = xd + acc[c];                      // EPS=0
        float t = fmaxf(fmaf(z, w1l, b1l), 0.f);
        float o = b2l;
#pragma unroll
        for (int j = 0; j < HID; ++j) o = fmaf(__shfl(t, j, 64), w2c[j], o);
        hout[((size_t)d * NCH + c) * HID + lane] = fmaxf(o, 0.f);  // inter-layer relu
    }
}

// ---------------- layers 1/2: CSR gather + on-the-fly edge embed ----------------
__global__ __launch_bounds__(256) void k_edge2(
    const float* __restrict__ ea, const int2* __restrict__ se, const int* __restrict__ row,
    const float* __restrict__ We, const float* __restrict__ be,
    const float* __restrict__ hin, float* __restrict__ agg)
{
    int lane = threadIdx.x & 63;
    float wcol[EDIM];
#pragma unroll
    for (int dd = 0; dd < EDIM; ++dd) wcol[dd] = We[dd * HID + lane];
    float bel = be[lane];

    int d = (blockIdx.x * 256 + threadIdx.x) >> 6;
    if (d >= NN) return;

    float acc[NCH];
#pragma unroll
    for (int c = 0; c < NCH; ++c) acc[c] = 0.f;

    int p1 = row[d + 1];
    for (int p = row[d]; p < p1; ++p) {
        int2 sp = se[p];
        float r = (lane < EDIM) ? ea[(size_t)sp.y * EDIM + lane] : 0.f;
        float em = bel;
#pragma unroll
        for (int dd = 0; dd < EDIM; ++dd) em = fmaf(__shfl(r, dd, 64), wcol[dd], em);
        const float* hs = hin + (size_t)sp.x * (NCH * HID) + lane;
#pragma unroll
        for (int c = 0; c < NCH; ++c) acc[c] += fmaxf(hs[c * HID] + em, 0.f);
    }

    float* ad = agg + (size_t)d * (NCH * HID) + lane;
#pragma unroll
    for (int c = 0; c < NCH; ++c) ad[c * HID] = acc[c];
}

// ---------------- layers 1/2: node MLP 64 -> 64 -> OUT (wave per node) ----------------
template <int OUT, bool DORELU>
__global__ __launch_bounds__(256) void k_node2(
    const float* __restrict__ hin, const float* __restrict__ agg,
    const float* __restrict__ W1, const float* __restrict__ b1,
    const float* __restrict__ W2, const float* __restrict__ b2,
    float* __restrict__ hout)
{
    int lane = threadIdx.x & 63;
    float w1c[HID], w2c[HID];
#pragma unroll
    for (int j = 0; j < HID; ++j) w1c[j] = W1[j * HID + lane];
#pragma unroll
    for (int j = 0; j < HID; ++j) w2c[j] = (lane < OUT) ? W2[j * OUT + lane] : 0.f;
    float b1l = b1[lane];
    float b2l = (lane < OUT) ? b2[lane] : 0.f;

    int d = (blockIdx.x * 256 + threadIdx.x) >> 6;
    if (d >= NN) return;

#pragma unroll
    for (int c = 0; c < NCH; ++c) {
        size_t o = (size_t)d * NCH + c;
        float z = hin[o * HID + lane] + agg[o * HID + lane];
        float a1 = b1l;
#pragma unroll
        for (int j = 0; j < HID; ++j) a1 = fmaf(__shfl(z, j, 64), w1c[j], a1);
        float t = fmaxf(a1, 0.f);
        float a2 = b2l;
#pragma unroll
        for (int j = 0; j < HID; ++j) a2 = fmaf(__shfl(t, j, 64), w2c[j], a2);
        if (lane < OUT) hout[o * OUT + lane] = DORELU ? fmaxf(a2, 0.f) : a2;
    }
}

// ---------------- channel-sum pool + rho MLP 32 -> 64 -> 64 ----------------
__global__ __launch_bounds__(256) void k_rho(
    const float* __restrict__ h2,
    const float* __restrict__ Wr1, const float* __restrict__ br1,
    const float* __restrict__ Wr2, const float* __restrict__ br2,
    float* __restrict__ out)
{
    int lane = threadIdx.x & 63;
    float w1c[EDIM], w2c[HID];
#pragma unroll
    for (int j = 0; j < EDIM; ++j) w1c[j] = Wr1[j * HID + lane];
#pragma unroll
    for (int j = 0; j < HID; ++j) w2c[j] = Wr2[j * ODIM + lane];
    float b1l = br1[lane];
    float b2l = br2[lane];

    int d = (blockIdx.x * 256 + threadIdx.x) >> 6;
    if (d >= NN) return;

    float p = 0.f;
    if (lane < EDIM) {
#pragma unroll
        for (int c = 0; c < NCH; ++c) p += h2[((size_t)d * NCH + c) * EDIM + lane];
    }
    float a1 = b1l;
#pragma unroll
    for (int j = 0; j < EDIM; ++j) a1 = fmaf(__shfl(p, j, 64), w1c[j], a1);
    float t = fmaxf(a1, 0.f);
    float a2 = b2l;
#pragma unroll
    for (int j = 0; j < HID; ++j) a2 = fmaf(__shfl(t, j, 64), w2c[j], a2);
    out[(size_t)d * ODIM + lane] = a2;
}

extern "C" void kernel_launch(void* const* d_in, const int* in_sizes, int n_in,
                              void* d_out, int out_size, void* d_ws, size_t ws_size,
                              hipStream_t stream)
{
    const float* x   = (const float*)d_in[0];
    const float* ea  = (const float*)d_in[1];
    const int*   ei  = (const int*)d_in[2];
    const float* We0 = (const float*)d_in[3];
    const float* be0 = (const float*)d_in[4];
    const float* W10 = (const float*)d_in[5];
    const float* b10 = (const float*)d_in[6];
    const float* W20 = (const float*)d_in[7];
    const float* b20 = (const float*)d_in[8];
    const float* We1 = (const float*)d_in[9];
    const float* be1 = (const float*)d_in[10];
    const float* W11 = (const float*)d_in[11];
    const float* b11 = (const float*)d_in[12];
    const float* W21 = (const float*)d_in[13];
    const float* b21 = (const float*)d_in[14];
    const float* We2 = (const float*)d_in[15];
    const float* be2 = (const float*)d_in[16];
    const float* W12 = (const float*)d_in[17];
    const float* b12 = (const float*)d_in[18];
    const float* W22 = (const float*)d_in[19];
    const float* b22 = (const float*)d_in[20];
    const float* Wr1 = (const float*)d_in[21];
    const float* br1 = (const float*)d_in[22];
    const float* Wr2 = (const float*)d_in[23];
    const float* br2 = (const float*)d_in[24];
    float* out = (float*)d_out;

    // workspace layout (floats):
    // h   [8*N*64] = 10.24M   (node features, layout [n][c][f], in-place across layers)
    // agg [8*N*64] = 10.24M
    // h2  [8*N*32] =  5.12M
    // row [N+1] | cnt [N] | cursor [N] | pad | se [E int2]
    float* h   = (float*)d_ws;
    float* agg = h + (size_t)NCH * NN * HID;
    float* h2  = agg + (size_t)NCH * NN * HID;
    int*   row = (int*)(h2 + (size_t)NCH * NN * EDIM);
    int*   cnt = row + (NN + 1);
    int*   cursor = cnt + NN;
    int2*  se  = (int2*)(cursor + NN + 1);   // +1 pad keeps int2 8B-aligned (offsets are even anyway)

    // ---- CSR build (dst-grouped) ----
    hipMemsetAsync(cnt, 0, NN * sizeof(int), stream);
    k_hist<<<NE / 256, 256, 0, stream>>>(ei, cnt);
    k_scan<<<1, 512, 0, stream>>>(cnt, row, cursor);
    k_scatter<<<NE / 256, 256, 0, stream>>>(ei, cursor, se);

    const int NODE_BLOCKS = (NN * 64 + 255) / 256;   // one wave per node

    // ---- layer 0 (fused edges + MLP) ----
    k_layer0<<<NODE_BLOCKS, 256, 0, stream>>>(x, ea, se, row, We0, be0, W10, b10, W20, b20, h);

    // ---- layer 1 ----
    k_edge2<<<NODE_BLOCKS, 256, 0, stream>>>(ea, se, row, We1, be1, h, agg);
    k_node2<HID, true><<<NODE_BLOCKS, 256, 0, stream>>>(h, agg, W11, b11, W21, b21, h);

    // ---- layer 2 ----
    k_edge2<<<NODE_BLOCKS, 256, 0, stream>>>(ea, se, row, We2, be2, h, agg);
    k_node2<EDIM, false><<<NODE_BLOCKS, 256, 0, stream>>>(h, agg, W12, b12, W22, b22, h2);

    // ---- pool over channels + rho ----
    k_rho<<<NODE_BLOCKS, 256, 0, stream>>>(h2, Wr1, br1, Wr2, br2, out);
}

// Round 3
// 585.128 us; speedup vs baseline: 5.1234x; 2.4139x over previous
//
#include <hip/hip_runtime.h>

#define NN 20000
#define NE 640000
#define NCH 8
#define HID 64
#define EDIM 32
#define ODIM 64

#define CHUNK_CAP 386064   // rows per emb chunk buffer (E/2 + 66k pad, mult of 16)

typedef __attribute__((ext_vector_type(8))) short bf16x8;
typedef __attribute__((ext_vector_type(4))) float f32x4;

__device__ __forceinline__ float b2f(unsigned short u) {
    unsigned v = ((unsigned)u) << 16;
    return __builtin_bit_cast(float, v);
}
__device__ __forceinline__ unsigned short f2b(float f) {   // RNE
    unsigned u = __builtin_bit_cast(unsigned, f);
    unsigned r = (u + 0x7fffu + ((u >> 16) & 1u)) >> 16;
    return (unsigned short)r;
}
__device__ __forceinline__ f32x4 mfma16(bf16x8 a, bf16x8 b, f32x4 c) {
    return __builtin_amdgcn_mfma_f32_16x16x32_bf16(a, b, c, 0, 0, 0);
}
// B-fragment: lane(g=l>>4, r=l&15) holds B[k0+8g+j][n0+r], W row-major [K][ldn]
__device__ __forceinline__ bf16x8 load_bfrag(const unsigned short* W, int ldn, int k0, int n0, int lane) {
    int g = lane >> 4, r = lane & 15;
    bf16x8 f;
#pragma unroll
    for (int j = 0; j < 8; ++j) f[j] = (short)W[(k0 + 8 * g + j) * ldn + n0 + r];
    return f;
}

// ---------------- weight cast fp32 -> bf16 (one shot) ----------------
// bw layout (shorts): We1@0(2048) We2@2048 W11@4096(4096) W21@8192 W12@12288
//                     W22@16384(2048) W20@18432(4096) Wr1@22528(2048) Wr2@24576(4096)
__global__ __launch_bounds__(256) void k_prep(
    const float* We1, const float* We2, const float* W11, const float* W21,
    const float* W12, const float* W22, const float* W20, const float* Wr1,
    const float* Wr2, unsigned short* bw)
{
    int gid = blockIdx.x * 256 + threadIdx.x;
    const float* src; int off;
    if      (gid < 2048)  { src = We1; off = 0; }
    else if (gid < 4096)  { src = We2; off = 2048; }
    else if (gid < 8192)  { src = W11; off = 4096; }
    else if (gid < 12288) { src = W21; off = 8192; }
    else if (gid < 16384) { src = W12; off = 12288; }
    else if (gid < 18432) { src = W22; off = 16384; }
    else if (gid < 22528) { src = W20; off = 18432; }
    else if (gid < 24576) { src = Wr1; off = 22528; }
    else                  { src = Wr2; off = 24576; }
    bw[gid] = f2b(src[gid - off]);
}

// ---------------- CSR build ----------------
__global__ __launch_bounds__(256) void k_hist(const int* __restrict__ ei, int* __restrict__ cnt)
{
    int e = blockIdx.x * 256 + threadIdx.x;
    if (e < NE) atomicAdd(&cnt[ei[NE + e]], 1);
}

__global__ __launch_bounds__(512) void k_scan(const int* __restrict__ cnt,
                                              int* __restrict__ row, int* __restrict__ cursor)
{
    __shared__ int part[512];
    int t = threadIdx.x;
    int base = t * 40;
    int s = 0;
#pragma unroll
    for (int i = 0; i < 40; ++i) { int idx = base + i; if (idx < NN) s += cnt[idx]; }
    part[t] = s;
    __syncthreads();
    int v = s;
    for (int off = 1; off < 512; off <<= 1) {
        int add = (t >= off) ? part[t - off] : 0;
        __syncthreads();
        v += add;
        part[t] = v;
        __syncthreads();
    }
    int run = v - s;
    for (int i = 0; i < 40; ++i) {
        int idx = base + i;
        if (idx < NN) { row[idx] = run; cursor[idx] = run; run += cnt[idx]; }
    }
    if (t == 511) row[NN] = NE;
}

__global__ __launch_bounds__(256) void k_scatter(const int* __restrict__ ei,
                                                 int* __restrict__ cursor, int2* __restrict__ se)
{
    int e = blockIdx.x * 256 + threadIdx.x;
    if (e < NE) {
        int d = ei[NE + e];
        int pos = atomicAdd(&cursor[d], 1);
        se[pos] = make_int2(ei[e], e);
    }
}

// ---------------- layer-0 scalar edge embed, CSR order ----------------
__global__ __launch_bounds__(256) void k_emb0(
    const float* __restrict__ ea, const int2* __restrict__ se,
    const float* __restrict__ We0, const float* __restrict__ be0,
    float* __restrict__ emb0)
{
    int i = threadIdx.x & 31;
    int grp = (blockIdx.x * 256 + threadIdx.x) >> 5;
    int ngrp = (gridDim.x * 256) >> 5;
    float w = We0[i];
    float be = be0[0];
    for (int p = grp; p < NE; p += ngrp) {
        int eid = se[p].y;
        float v = ea[(size_t)eid * 32 + i] * w;
        v += __shfl_xor(v, 16, 64);
        v += __shfl_xor(v, 8, 64);
        v += __shfl_xor(v, 4, 64);
        v += __shfl_xor(v, 2, 64);
        v += __shfl_xor(v, 1, 64);
        if (i == 0) emb0[p] = v + be;
    }
}

// ---------------- layer-0 gather: thread per (node, ch), z0 = +-x + agg ----------------
__global__ __launch_bounds__(256) void k_l0_gather(
    const float* __restrict__ x, const int2* __restrict__ se,
    const int* __restrict__ row, const float* __restrict__ emb0,
    float* __restrict__ z0)
{
    int gid = blockIdx.x * 256 + threadIdx.x;
    if (gid >= NN * NCH) return;
    int d = gid >> 3, c = gid & 7;
    int k = c & 3;
    float sgn = (c >= 4) ? -1.f : 1.f;
    float acc = 0.f;
    int p1 = row[d + 1];
    for (int p = row[d]; p < p1; ++p) {
        float xs = x[k * NN + se[p].x];
        acc += fmaxf(sgn * xs + emb0[p], 0.f);
    }
    z0[gid] = sgn * x[k * NN + d] + acc;
}

// ---------------- layer-0 MLP: t = relu(z0*W1+b1) (outer), h = relu(t@W2+b2) ----------------
__global__ __launch_bounds__(256) void k_l0_mlp(
    const float* __restrict__ z0,
    const float* __restrict__ W1, const float* __restrict__ b1,
    const unsigned short* __restrict__ W2b, const float* __restrict__ b2,
    unsigned short* __restrict__ hout)
{
    constexpr int S = 72;
    __shared__ short lds[4][16 * S];
    int lane = threadIdx.x & 63, wid = threadIdx.x >> 6, g = lane >> 4, r = lane & 15;
    short* L = lds[wid];
    bf16x8 w2f[2][4];
#pragma unroll
    for (int kk = 0; kk < 2; ++kk)
#pragma unroll
        for (int t = 0; t < 4; ++t) w2f[kk][t] = load_bfrag(W2b, 64, kk * 32, t * 16, lane);
    float b2v[4];
#pragma unroll
    for (int t = 0; t < 4; ++t) b2v[t] = b2[t * 16 + r];
    float w1a[8], w1b[8], b1a[8], b1b[8];
#pragma unroll
    for (int j = 0; j < 8; ++j) {
        w1a[j] = W1[8 * g + j];      b1a[j] = b1[8 * g + j];
        w1b[j] = W1[32 + 8 * g + j]; b1b[j] = b1[32 + 8 * g + j];
    }
    int tile = blockIdx.x * 4 + wid;      // 10000 tiles exactly
    int row0 = tile * 16;
    float zv = z0[row0 + r];
    bf16x8 a0, a1;
#pragma unroll
    for (int j = 0; j < 8; ++j) {
        a0[j] = (short)f2b(fmaxf(fmaf(zv, w1a[j], b1a[j]), 0.f));
        a1[j] = (short)f2b(fmaxf(fmaf(zv, w1b[j], b1b[j]), 0.f));
    }
    f32x4 c2[4];
#pragma unroll
    for (int t = 0; t < 4; ++t) {
        f32x4 c = {0.f, 0.f, 0.f, 0.f};
        c = mfma16(a0, w2f[0][t], c);
        c = mfma16(a1, w2f[1][t], c);
        c2[t] = c;
    }
#pragma unroll
    for (int t = 0; t < 4; ++t)
#pragma unroll
        for (int i = 0; i < 4; ++i)
            L[(4 * g + i) * S + t * 16 + r] = (short)f2b(fmaxf(c2[t][i] + b2v[t], 0.f));
    asm volatile("" ::: "memory");
    bf16x8 o0 = *(const bf16x8*)(L + r * S + 8 * g);
    bf16x8 o1 = *(const bf16x8*)(L + r * S + 32 + 8 * g);
    *(bf16x8*)(hout + (size_t)(row0 + r) * 64 + 8 * g) = o0;
    *(bf16x8*)(hout + (size_t)(row0 + r) * 64 + 32 + 8 * g) = o1;
}

// ---------------- edge embed GEMM (chunked): emb[p-p0] = ea[se[p].y] @ We + be ----------------
__global__ __launch_bounds__(256) void k_emb(
    const float* __restrict__ ea, const int2* __restrict__ se,
    const int* __restrict__ row,
    const unsigned short* __restrict__ Web, const float* __restrict__ be,
    unsigned short* __restrict__ emb, int dlo, int dhi)
{
    constexpr int S = 72;
    __shared__ short lds[4][16 * S];
    int lane = threadIdx.x & 63, wid = threadIdx.x >> 6, g = lane >> 4, r = lane & 15;
    int p0 = row[dlo], p1 = row[dhi];
    int tile = blockIdx.x * 4 + wid;
    if (p0 + tile * 16 >= p1) return;
    bf16x8 wf[4];
#pragma unroll
    for (int t = 0; t < 4; ++t) wf[t] = load_bfrag(Web, 64, 0, t * 16, lane);
    float bev[4];
#pragma unroll
    for (int t = 0; t < 4; ++t) bev[t] = be[t * 16 + r];
    short* L = lds[wid];

    int prow = p0 + tile * 16 + r;
    if (prow >= NE) prow = NE - 1;
    int eid = se[prow].y;
    f32x4 v0 = *(const f32x4*)(ea + (size_t)eid * 32 + 8 * g);
    f32x4 v1 = *(const f32x4*)(ea + (size_t)eid * 32 + 8 * g + 4);
    bf16x8 af;
#pragma unroll
    for (int j = 0; j < 4; ++j) { af[j] = (short)f2b(v0[j]); af[4 + j] = (short)f2b(v1[j]); }
    f32x4 c[4];
#pragma unroll
    for (int t = 0; t < 4; ++t) {
        f32x4 cc = {0.f, 0.f, 0.f, 0.f};
        c[t] = mfma16(af, wf[t], cc);
    }
#pragma unroll
    for (int t = 0; t < 4; ++t)
#pragma unroll
        for (int i = 0; i < 4; ++i)
            L[(4 * g + i) * S + t * 16 + r] = (short)f2b(c[t][i] + bev[t]);
    asm volatile("" ::: "memory");
    bf16x8 o0 = *(const bf16x8*)(L + r * S + 8 * g);
    bf16x8 o1 = *(const bf16x8*)(L + r * S + 32 + 8 * g);
    size_t orow = (size_t)(tile * 16 + r);
    *(bf16x8*)(emb + orow * 64 + 8 * g) = o0;
    *(bf16x8*)(emb + orow * 64 + 32 + 8 * g) = o1;
}

// ---------------- gather: wave per dst node; z = h_dst + sum relu(h_src + emb) ----------------
__global__ __launch_bounds__(256) void k_gather(
    const int2* __restrict__ se, const int* __restrict__ row,
    const unsigned short* __restrict__ emb,
    const unsigned short* __restrict__ h,
    unsigned short* __restrict__ z, int dlo, int dhi)
{
    int lane = threadIdx.x & 63;
    int d = dlo + ((blockIdx.x * 256 + threadIdx.x) >> 6);
    if (d >= dhi) return;
    int p0g = row[dlo];
    int p0 = row[d], p1 = row[d + 1];
    float acc[NCH];
#pragma unroll
    for (int c = 0; c < NCH; ++c) acc[c] = 0.f;
    for (int p = p0; p < p1; ++p) {
        int src = se[p].x;
        float em = b2f(emb[(size_t)(p - p0g) * 64 + lane]);
        const unsigned short* hp = h + (size_t)src * 512 + lane;
#pragma unroll
        for (int c = 0; c < NCH; ++c) {
            float hv = b2f(hp[c * 64]);
            acc[c] += fmaxf(hv + em, 0.f);
        }
    }
    const unsigned short* hd = h + (size_t)d * 512 + lane;
    unsigned short* zd = z + (size_t)d * 512 + lane;
#pragma unroll
    for (int c = 0; c < NCH; ++c)
        zd[c * 64] = f2b(b2f(hd[c * 64]) + acc[c]);
}

// ---------------- node MLP: h = [relu](relu(z@W1+b1)@W2+b2), MFMA ----------------
template <int OUT, bool RELU2>
__global__ __launch_bounds__(256) void k_mlp(
    const unsigned short* __restrict__ z,
    const unsigned short* __restrict__ W1b, const float* __restrict__ b1,
    const unsigned short* __restrict__ W2b, const float* __restrict__ b2,
    unsigned short* __restrict__ hout)
{
    constexpr int S1 = 72;
    constexpr int S2 = (OUT == 64) ? 72 : 40;
    constexpr int NT2 = OUT / 16;
    __shared__ short lds[4][16 * S1];
    int lane = threadIdx.x & 63, wid = threadIdx.x >> 6, g = lane >> 4, r = lane & 15;
    short* L = lds[wid];

    bf16x8 w1f[2][4];
#pragma unroll
    for (int kk = 0; kk < 2; ++kk)
#pragma unroll
        for (int t = 0; t < 4; ++t) w1f[kk][t] = load_bfrag(W1b, 64, kk * 32, t * 16, lane);
    bf16x8 w2f[2][NT2];
#pragma unroll
    for (int kk = 0; kk < 2; ++kk)
#pragma unroll
        for (int t = 0; t < NT2; ++t) w2f[kk][t] = load_bfrag(W2b, OUT, kk * 32, t * 16, lane);
    float b1v[4], b2v[NT2];
#pragma unroll
    for (int t = 0; t < 4; ++t) b1v[t] = b1[t * 16 + r];
#pragma unroll
    for (int t = 0; t < NT2; ++t) b2v[t] = b2[t * 16 + r];

    int tile = blockIdx.x * 4 + wid;      // 10000 tiles exactly
    int row0 = tile * 16;

    bf16x8 a0 = *(const bf16x8*)(z + (size_t)(row0 + r) * 64 + 8 * g);
    bf16x8 a1 = *(const bf16x8*)(z + (size_t)(row0 + r) * 64 + 32 + 8 * g);
    f32x4 c1[4];
#pragma unroll
    for (int t = 0; t < 4; ++t) {
        f32x4 c = {0.f, 0.f, 0.f, 0.f};
        c = mfma16(a0, w1f[0][t], c);
        c = mfma16(a1, w1f[1][t], c);
        c1[t] = c;
    }
#pragma unroll
    for (int t = 0; t < 4; ++t)
#pragma unroll
        for (int i = 0; i < 4; ++i)
            L[(4 * g + i) * S1 + t * 16 + r] = (short)f2b(fmaxf(c1[t][i] + b1v[t], 0.f));
    asm volatile("" ::: "memory");
    bf16x8 t0 = *(const bf16x8*)(L + r * S1 + 8 * g);
    bf16x8 t1 = *(const bf16x8*)(L + r * S1 + 32 + 8 * g);
    f32x4 c2[NT2];
#pragma unroll
    for (int t = 0; t < NT2; ++t) {
        f32x4 c = {0.f, 0.f, 0.f, 0.f};
        c = mfma16(t0, w2f[0][t], c);
        c = mfma16(t1, w2f[1][t], c);
        c2[t] = c;
    }
    asm volatile("" ::: "memory");
#pragma unroll
    for (int t = 0; t < NT2; ++t)
#pragma unroll
        for (int i = 0; i < 4; ++i) {
            float v = c2[t][i] + b2v[t];
            if (RELU2) v = fmaxf(v, 0.f);
            L[(4 * g + i) * S2 + t * 16 + r] = (short)f2b(v);
        }
    asm volatile("" ::: "memory");
    if (OUT == 64) {
        bf16x8 o0 = *(const bf16x8*)(L + r * S2 + 8 * g);
        bf16x8 o1 = *(const bf16x8*)(L + r * S2 + 32 + 8 * g);
        *(bf16x8*)(hout + (size_t)(row0 + r) * 64 + 8 * g) = o0;
        *(bf16x8*)(hout + (size_t)(row0 + r) * 64 + 32 + 8 * g) = o1;
    } else {
        bf16x8 o0 = *(const bf16x8*)(L + r * S2 + 8 * g);
        *(bf16x8*)(hout + (size_t)(row0 + r) * OUT + 8 * g) = o0;
    }
}

// ---------------- rho: pool channels + 2-GEMM MLP, fp32 out ----------------
__global__ __launch_bounds__(256) void k_rho(
    const unsigned short* __restrict__ h2,
    const unsigned short* __restrict__ Wr1b, const float* __restrict__ br1,
    const unsigned short* __restrict__ Wr2b, const float* __restrict__ br2,
    float* __restrict__ out)
{
    constexpr int S = 72;
    __shared__ short lds[4][16 * S];
    int lane = threadIdx.x & 63, wid = threadIdx.x >> 6, g = lane >> 4, r = lane & 15;
    short* L = lds[wid];
    int tile = blockIdx.x * 4 + wid;      // 1250 tiles
    if (tile * 16 >= NN) return;
    bf16x8 w1f[4], w2f[2][4];
#pragma unroll
    for (int t = 0; t < 4; ++t) w1f[t] = load_bfrag(Wr1b, 64, 0, t * 16, lane);
#pragma unroll
    for (int kk = 0; kk < 2; ++kk)
#pragma unroll
        for (int t = 0; t < 4; ++t) w2f[kk][t] = load_bfrag(Wr2b, 64, kk * 32, t * 16, lane);
    float b1v[4], b2v[4];
#pragma unroll
    for (int t = 0; t < 4; ++t) { b1v[t] = br1[t * 16 + r]; b2v[t] = br2[t * 16 + r]; }

    int n = tile * 16 + r;
    float s[8] = {0.f, 0.f, 0.f, 0.f, 0.f, 0.f, 0.f, 0.f};
#pragma unroll
    for (int c = 0; c < NCH; ++c) {
        bf16x8 hv = *(const bf16x8*)(h2 + ((size_t)n * 8 + c) * 32 + 8 * g);
#pragma unroll
        for (int j = 0; j < 8; ++j) s[j] += b2f((unsigned short)hv[j]);
    }
    bf16x8 af;
#pragma unroll
    for (int j = 0; j < 8; ++j) af[j] = (short)f2b(s[j]);
    f32x4 c1[4];
#pragma unroll
    for (int t = 0; t < 4; ++t) {
        f32x4 c = {0.f, 0.f, 0.f, 0.f};
        c1[t] = mfma16(af, w1f[t], c);
    }
#pragma unroll
    for (int t = 0; t < 4; ++t)
#pragma unroll
        for (int i = 0; i < 4; ++i)
            L[(4 * g + i) * S + t * 16 + r] = (short)f2b(fmaxf(c1[t][i] + b1v[t], 0.f));
    asm volatile("" ::: "memory");
    bf16x8 t0 = *(const bf16x8*)(L + r * S + 8 * g);
    bf16x8 t1 = *(const bf16x8*)(L + r * S + 32 + 8 * g);
    f32x4 c2[4];
#pragma unroll
    for (int t = 0; t < 4; ++t) {
        f32x4 c = {0.f, 0.f, 0.f, 0.f};
        c = mfma16(t0, w2f[0][t], c);
        c = mfma16(t1, w2f[1][t], c);
        c2[t] = c;
    }
    int nb = tile * 16;
#pragma unroll
    for (int t = 0; t < 4; ++t)
#pragma unroll
        for (int i = 0; i < 4; ++i)
            out[(size_t)(nb + 4 * g + i) * 64 + t * 16 + r] = c2[t][i] + b2v[t];
}

extern "C" void kernel_launch(void* const* d_in, const int* in_sizes, int n_in,
                              void* d_out, int out_size, void* d_ws, size_t ws_size,
                              hipStream_t stream)
{
    const float* x   = (const float*)d_in[0];
    const float* ea  = (const float*)d_in[1];
    const int*   ei  = (const int*)d_in[2];
    const float* We0 = (const float*)d_in[3];
    const float* be0 = (const float*)d_in[4];
    const float* W10 = (const float*)d_in[5];
    const float* b10 = (const float*)d_in[6];
    const float* W20 = (const float*)d_in[7];
    const float* b20 = (const float*)d_in[8];
    const float* We1 = (const float*)d_in[9];
    const float* be1 = (const float*)d_in[10];
    const float* W11 = (const float*)d_in[11];
    const float* b11 = (const float*)d_in[12];
    const float* W21 = (const float*)d_in[13];
    const float* b21 = (const float*)d_in[14];
    const float* We2 = (const float*)d_in[15];
    const float* be2 = (const float*)d_in[16];
    const float* W12 = (const float*)d_in[17];
    const float* b12 = (const float*)d_in[18];
    const float* W22 = (const float*)d_in[19];
    const float* b22 = (const float*)d_in[20];
    const float* Wr1 = (const float*)d_in[21];
    const float* br1 = (const float*)d_in[22];
    const float* Wr2 = (const float*)d_in[23];
    const float* br2 = (const float*)d_in[24];
    float* out = (float*)d_out;

    // ---- workspace layout (all offsets 128B-aligned) ----
    char* base = (char*)d_ws;
    unsigned short* h    = (unsigned short*)base;                   base += (size_t)160000 * 64 * 2;   // 20.48 MB
    unsigned short* z    = (unsigned short*)base;                   base += (size_t)160000 * 64 * 2;   // 20.48 MB
    unsigned short* embC = (unsigned short*)base;                   base += (size_t)CHUNK_CAP * 64 * 2;// 49.42 MB
    float* emb0          = (float*)base;                            base += (size_t)NE * 4;            // 2.56 MB
    float* z0            = (float*)base;                            base += (size_t)160000 * 4;        // 0.64 MB
    int2* se             = (int2*)base;                             base += (size_t)NE * 8;            // 5.12 MB
    int* row             = (int*)base;                              base += 80128;
    int* cnt             = (int*)base;                              base += 80128;
    int* cursor          = (int*)base;                              base += 80128;
    unsigned short* bw   = (unsigned short*)base;                   // 57 KB

    const unsigned short* bWe1 = bw;
    const unsigned short* bWe2 = bw + 2048;
    const unsigned short* bW11 = bw + 4096;
    const unsigned short* bW21 = bw + 8192;
    const unsigned short* bW12 = bw + 12288;
    const unsigned short* bW22 = bw + 16384;
    const unsigned short* bW20 = bw + 18432;
    const unsigned short* bWr1 = bw + 22528;
    const unsigned short* bWr2 = bw + 24576;

    // ---- prep: weights -> bf16, CSR build ----
    k_prep<<<112, 256, 0, stream>>>(We1, We2, W11, W21, W12, W22, W20, Wr1, Wr2, bw);
    hipMemsetAsync(cnt, 0, NN * sizeof(int), stream);
    k_hist<<<NE / 256, 256, 0, stream>>>(ei, cnt);
    k_scan<<<1, 512, 0, stream>>>(cnt, row, cursor);
    k_scatter<<<NE / 256, 256, 0, stream>>>(ei, cursor, se);

    // ---- layer 0 ----
    k_emb0<<<1024, 256, 0, stream>>>(ea, se, We0, be0, emb0);
    k_l0_gather<<<(NN * NCH + 255) / 256, 256, 0, stream>>>(x, se, row, emb0, z0);
    k_l0_mlp<<<2500, 256, 0, stream>>>(z0, W10, b10, bW20, b20, h);

    const int EMB_BLOCKS = (CHUNK_CAP / 16 + 3) / 4;   // 6033
    const int GATH_BLOCKS = (NN / 2) / 4;              // 2500 (wave per node, 4 waves/block)

    // ---- layer 1 (chunked over dst halves) ----
    k_emb<<<EMB_BLOCKS, 256, 0, stream>>>(ea, se, row, bWe1, be1, embC, 0, NN / 2);
    k_gather<<<GATH_BLOCKS, 256, 0, stream>>>(se, row, embC, h, z, 0, NN / 2);
    k_emb<<<EMB_BLOCKS, 256, 0, stream>>>(ea, se, row, bWe1, be1, embC, NN / 2, NN);
    k_gather<<<GATH_BLOCKS, 256, 0, stream>>>(se, row, embC, h, z, NN / 2, NN);
    k_mlp<64, true><<<2500, 256, 0, stream>>>(z, bW11, b11, bW21, b21, h);

    // ---- layer 2 ----
    k_emb<<<EMB_BLOCKS, 256, 0, stream>>>(ea, se, row, bWe2, be2, embC, 0, NN / 2);
    k_gather<<<GATH_BLOCKS, 256, 0, stream>>>(se, row, embC, h, z, 0, NN / 2);
    k_emb<<<EMB_BLOCKS, 256, 0, stream>>>(ea, se, row, bWe2, be2, embC, NN / 2, NN);
    k_gather<<<GATH_BLOCKS, 256, 0, stream>>>(se, row, embC, h, z, NN / 2, NN);
    k_mlp<32, false><<<2500, 256, 0, stream>>>(z, bW12, b12, bW22, b22, h);  // h2 aliases h

    // ---- pool + rho ----
    k_rho<<<313, 256, 0, stream>>>(h, bWr1, br1, bWr2, br2, out);
}

// Round 4
// 420.228 us; speedup vs baseline: 7.1338x; 1.3924x over previous
//
#include <hip/hip_runtime.h>

#define NN 20000
#define NE 640000
#define NCH 8
#define HID 64
#define EDIM 32
#define ODIM 64

typedef __attribute__((ext_vector_type(8))) short bf16x8;
typedef __attribute__((ext_vector_type(4))) float f32x4;

__device__ __forceinline__ float b2f(unsigned short u) {
    unsigned v = ((unsigned)u) << 16;
    return __builtin_bit_cast(float, v);
}
__device__ __forceinline__ unsigned short f2b(float f) {   // RNE
    unsigned u = __builtin_bit_cast(unsigned, f);
    unsigned r = (u + 0x7fffu + ((u >> 16) & 1u)) >> 16;
    return (unsigned short)r;
}
__device__ __forceinline__ f32x4 mfma16(bf16x8 a, bf16x8 b, f32x4 c) {
    return __builtin_amdgcn_mfma_f32_16x16x32_bf16(a, b, c, 0, 0, 0);
}
// B-fragment: lane(g=l>>4, r=l&15) holds B[k0+8g+j][n0+r], W row-major [K][ldn]
__device__ __forceinline__ bf16x8 load_bfrag(const unsigned short* W, int ldn, int k0, int n0, int lane) {
    int g = lane >> 4, r = lane & 15;
    bf16x8 f;
#pragma unroll
    for (int j = 0; j < 8; ++j) f[j] = (short)W[(k0 + 8 * g + j) * ldn + n0 + r];
    return f;
}

// ---------------- weight cast fp32 -> bf16 (one shot) ----------------
__global__ __launch_bounds__(256) void k_prep(
    const float* We1, const float* We2, const float* W11, const float* W21,
    const float* W12, const float* W22, const float* W20, const float* Wr1,
    const float* Wr2, unsigned short* bw)
{
    int gid = blockIdx.x * 256 + threadIdx.x;
    const float* src; int off;
    if      (gid < 2048)  { src = We1; off = 0; }
    else if (gid < 4096)  { src = We2; off = 2048; }
    else if (gid < 8192)  { src = W11; off = 4096; }
    else if (gid < 12288) { src = W21; off = 8192; }
    else if (gid < 16384) { src = W12; off = 12288; }
    else if (gid < 18432) { src = W22; off = 16384; }
    else if (gid < 22528) { src = W20; off = 18432; }
    else if (gid < 24576) { src = Wr1; off = 22528; }
    else                  { src = Wr2; off = 24576; }
    bw[gid] = f2b(src[gid - off]);
}

// ---------------- CSR build ----------------
__global__ __launch_bounds__(256) void k_hist(const int* __restrict__ ei, int* __restrict__ cnt)
{
    int e = blockIdx.x * 256 + threadIdx.x;
    if (e < NE) atomicAdd(&cnt[ei[NE + e]], 1);
}

__global__ __launch_bounds__(512) void k_scan(const int* __restrict__ cnt,
                                              int* __restrict__ row, int* __restrict__ cursor)
{
    __shared__ int part[512];
    int t = threadIdx.x;
    int base = t * 40;
    int s = 0;
#pragma unroll
    for (int i = 0; i < 40; ++i) { int idx = base + i; if (idx < NN) s += cnt[idx]; }
    part[t] = s;
    __syncthreads();
    int v = s;
    for (int off = 1; off < 512; off <<= 1) {
        int add = (t >= off) ? part[t - off] : 0;
        __syncthreads();
        v += add;
        part[t] = v;
        __syncthreads();
    }
    int run = v - s;
    for (int i = 0; i < 40; ++i) {
        int idx = base + i;
        if (idx < NN) { row[idx] = run; cursor[idx] = run; run += cnt[idx]; }
    }
    if (t == 511) row[NN] = NE;
}

__global__ __launch_bounds__(256) void k_scatter(const int* __restrict__ ei,
                                                 int* __restrict__ cursor, int2* __restrict__ se)
{
    int e = blockIdx.x * 256 + threadIdx.x;
    if (e < NE) {
        int d = ei[NE + e];
        int pos = atomicAdd(&cursor[d], 1);
        se[pos] = make_int2(ei[e], e);
    }
}

// ---------------- permute ea into CSR order (bf16) + layer-0 scalar embed ----------------
__global__ __launch_bounds__(256) void k_permea(
    const float* __restrict__ ea, const int2* __restrict__ se,
    const float* __restrict__ We0, const float* __restrict__ be0,
    unsigned short* __restrict__ eap, float* __restrict__ emb0)
{
    int p = blockIdx.x * 256 + threadIdx.x;
    if (p >= NE) return;
    int eid = se[p].y;
    const f32x4* s4 = (const f32x4*)(ea + (size_t)eid * 32);
    float e0 = be0[0];
#pragma unroll
    for (int h = 0; h < 4; ++h) {
        f32x4 a = s4[2 * h], b = s4[2 * h + 1];
        bf16x8 o;
#pragma unroll
        for (int j = 0; j < 4; ++j) {
            e0 = fmaf(a[j], We0[h * 8 + j], e0);
            e0 = fmaf(b[j], We0[h * 8 + 4 + j], e0);
            o[j] = (short)f2b(a[j]);
            o[4 + j] = (short)f2b(b[j]);
        }
        *(bf16x8*)(eap + (size_t)p * 32 + h * 8) = o;
    }
    emb0[p] = e0;
}

// ---------------- x transpose: xt[node][4] ----------------
__global__ __launch_bounds__(256) void k_xt(const float* __restrict__ x, float* __restrict__ xt)
{
    int n = blockIdx.x * 256 + threadIdx.x;
    if (n < NN) {
        f32x4 v = {x[n], x[NN + n], x[2 * NN + n], x[3 * NN + n]};
        *(f32x4*)(xt + (size_t)n * 4) = v;
    }
}

// ---------------- layer-0 gather: thread per (node, ch) ----------------
__global__ __launch_bounds__(256) void k_l0_gather(
    const float* __restrict__ xt, const int2* __restrict__ se,
    const int* __restrict__ row, const float* __restrict__ emb0,
    float* __restrict__ z0)
{
    int gid = blockIdx.x * 256 + threadIdx.x;
    if (gid >= NN * NCH) return;
    int d = gid >> 3, c = gid & 7;
    int k = c & 3;
    float sgn = (c >= 4) ? -1.f : 1.f;
    float acc = 0.f;
    int p1 = row[d + 1];
    for (int p = row[d]; p < p1; ++p) {
        float xs = xt[(size_t)se[p].x * 4 + k];
        acc += fmaxf(sgn * xs + emb0[p], 0.f);
    }
    z0[gid] = sgn * xt[(size_t)d * 4 + k] + acc;
}

// ---------------- layer-0 MLP -> hT [node][feat][ch] ----------------
__global__ __launch_bounds__(256) void k_l0_mlp(
    const float* __restrict__ z0,
    const float* __restrict__ W1, const float* __restrict__ b1,
    const unsigned short* __restrict__ W2b, const float* __restrict__ b2,
    unsigned short* __restrict__ hT)
{
    constexpr int S = 72;
    __shared__ short lds[4][16 * S];
    int lane = threadIdx.x & 63, wid = threadIdx.x >> 6, g = lane >> 4, r = lane & 15;
    short* L = lds[wid];
    bf16x8 w2f[2][4];
#pragma unroll
    for (int kk = 0; kk < 2; ++kk)
#pragma unroll
        for (int t = 0; t < 4; ++t) w2f[kk][t] = load_bfrag(W2b, 64, kk * 32, t * 16, lane);
    float b2v[4];
#pragma unroll
    for (int t = 0; t < 4; ++t) b2v[t] = b2[t * 16 + r];
    float w1a[8], w1b[8], b1a[8], b1b[8];
#pragma unroll
    for (int j = 0; j < 8; ++j) {
        w1a[j] = W1[8 * g + j];      b1a[j] = b1[8 * g + j];
        w1b[j] = W1[32 + 8 * g + j]; b1b[j] = b1[32 + 8 * g + j];
    }
    int tile = blockIdx.x * 4 + wid;      // 10000 tiles
    int row0 = tile * 16;
    float zv = z0[row0 + r];
    bf16x8 a0, a1;
#pragma unroll
    for (int j = 0; j < 8; ++j) {
        a0[j] = (short)f2b(fmaxf(fmaf(zv, w1a[j], b1a[j]), 0.f));
        a1[j] = (short)f2b(fmaxf(fmaf(zv, w1b[j], b1b[j]), 0.f));
    }
    f32x4 c2[4];
#pragma unroll
    for (int t = 0; t < 4; ++t) {
        f32x4 c = {0.f, 0.f, 0.f, 0.f};
        c = mfma16(a0, w2f[0][t], c);
        c = mfma16(a1, w2f[1][t], c);
        c2[t] = c;
    }
#pragma unroll
    for (int t = 0; t < 4; ++t)
#pragma unroll
        for (int i = 0; i < 4; ++i)
            L[(4 * g + i) * S + t * 16 + r] = (short)f2b(fmaxf(c2[t][i] + b2v[t], 0.f));
    asm volatile("" ::: "memory");
    int node0 = tile * 2;
#pragma unroll
    for (int half = 0; half < 2; ++half) {
        bf16x8 v;
#pragma unroll
        for (int c = 0; c < 8; ++c) v[c] = L[(half * 8 + c) * S + lane];
        *(bf16x8*)(hT + (size_t)(node0 + half) * 512 + lane * 8) = v;
    }
}

// ---------------- fused gather: emb MFMA in-wave + h-row gather ----------------
__global__ __launch_bounds__(256) void k_gather_f(
    const int2* __restrict__ se, const int* __restrict__ row,
    const unsigned short* __restrict__ eap,
    const unsigned short* __restrict__ Web, const float* __restrict__ be,
    const unsigned short* __restrict__ hT, unsigned short* __restrict__ z)
{
    constexpr int S = 72;
    __shared__ short lds[4][16 * S];
    int lane = threadIdx.x & 63, wid = threadIdx.x >> 6, g = lane >> 4, r = lane & 15;
    short* L = lds[wid];
    bf16x8 wf[4];
#pragma unroll
    for (int t = 0; t < 4; ++t) wf[t] = load_bfrag(Web, 64, 0, t * 16, lane);
    float bev[4];
#pragma unroll
    for (int t = 0; t < 4; ++t) bev[t] = be[t * 16 + r];

    int d = blockIdx.x * 4 + wid;     // 5000 blocks x 4 waves = 20000
    int p0 = row[d], p1 = row[d + 1];
    float acc[NCH];
#pragma unroll
    for (int c = 0; c < NCH; ++c) acc[c] = 0.f;

    for (int p = p0; p < p1; p += 16) {
        int pp = p + r;
        if (pp >= p1) pp = p1 - 1;
        bf16x8 af = *(const bf16x8*)(eap + (size_t)pp * 32 + 8 * g);
        int sv = se[pp].x;            // lane r holds src of edge p+r
        f32x4 c[4];
#pragma unroll
        for (int t = 0; t < 4; ++t) {
            f32x4 cc = {0.f, 0.f, 0.f, 0.f};
            c[t] = mfma16(af, wf[t], cc);
        }
#pragma unroll
        for (int t = 0; t < 4; ++t)
#pragma unroll
            for (int i = 0; i < 4; ++i)
                L[(4 * g + i) * S + t * 16 + r] = (short)f2b(c[t][i] + bev[t]);
        asm volatile("" ::: "memory");
        int ne = p1 - p; if (ne > 16) ne = 16;
        for (int q = 0; q < ne; ++q) {
            int src = __shfl(sv, q, 64);
            float em = b2f((unsigned short)L[q * S + lane]);
            bf16x8 hv = *(const bf16x8*)(hT + (size_t)src * 512 + lane * 8);
#pragma unroll
            for (int c2 = 0; c2 < NCH; ++c2)
                acc[c2] += fmaxf(b2f((unsigned short)hv[c2]) + em, 0.f);
        }
        asm volatile("" ::: "memory");
    }

    bf16x8 hd = *(const bf16x8*)(hT + (size_t)d * 512 + lane * 8);
#pragma unroll
    for (int c2 = 0; c2 < NCH; ++c2)
        z[((size_t)d * 8 + c2) * 64 + lane] = f2b(b2f((unsigned short)hd[c2]) + acc[c2]);
}

// ---------------- node MLP: z -> (hT | h2-rows) ----------------
template <int OUT, bool RELU2, bool TOHT>
__global__ __launch_bounds__(256) void k_mlp(
    const unsigned short* __restrict__ z,
    const unsigned short* __restrict__ W1b, const float* __restrict__ b1,
    const unsigned short* __restrict__ W2b, const float* __restrict__ b2,
    unsigned short* __restrict__ hout)
{
    constexpr int S1 = 72;
    constexpr int S2 = (OUT == 64) ? 72 : 40;
    constexpr int NT2 = OUT / 16;
    __shared__ short lds[4][16 * S1];
    int lane = threadIdx.x & 63, wid = threadIdx.x >> 6, g = lane >> 4, r = lane & 15;
    short* L = lds[wid];

    bf16x8 w1f[2][4];
#pragma unroll
    for (int kk = 0; kk < 2; ++kk)
#pragma unroll
        for (int t = 0; t < 4; ++t) w1f[kk][t] = load_bfrag(W1b, 64, kk * 32, t * 16, lane);
    bf16x8 w2f[2][NT2];
#pragma unroll
    for (int kk = 0; kk < 2; ++kk)
#pragma unroll
        for (int t = 0; t < NT2; ++t) w2f[kk][t] = load_bfrag(W2b, OUT, kk * 32, t * 16, lane);
    float b1v[4], b2v[NT2];
#pragma unroll
    for (int t = 0; t < 4; ++t) b1v[t] = b1[t * 16 + r];
#pragma unroll
    for (int t = 0; t < NT2; ++t) b2v[t] = b2[t * 16 + r];

    int tile = blockIdx.x * 4 + wid;      // 10000 tiles
    int row0 = tile * 16;

    bf16x8 a0 = *(const bf16x8*)(z + (size_t)(row0 + r) * 64 + 8 * g);
    bf16x8 a1 = *(const bf16x8*)(z + (size_t)(row0 + r) * 64 + 32 + 8 * g);
    f32x4 c1[4];
#pragma unroll
    for (int t = 0; t < 4; ++t) {
        f32x4 c = {0.f, 0.f, 0.f, 0.f};
        c = mfma16(a0, w1f[0][t], c);
        c = mfma16(a1, w1f[1][t], c);
        c1[t] = c;
    }
#pragma unroll
    for (int t = 0; t < 4; ++t)
#pragma unroll
        for (int i = 0; i < 4; ++i)
            L[(4 * g + i) * S1 + t * 16 + r] = (short)f2b(fmaxf(c1[t][i] + b1v[t], 0.f));
    asm volatile("" ::: "memory");
    bf16x8 t0 = *(const bf16x8*)(L + r * S1 + 8 * g);
    bf16x8 t1 = *(const bf16x8*)(L + r * S1 + 32 + 8 * g);
    f32x4 c2[NT2];
#pragma unroll
    for (int t = 0; t < NT2; ++t) {
        f32x4 c = {0.f, 0.f, 0.f, 0.f};
        c = mfma16(t0, w2f[0][t], c);
        c = mfma16(t1, w2f[1][t], c);
        c2[t] = c;
    }
    asm volatile("" ::: "memory");
#pragma unroll
    for (int t = 0; t < NT2; ++t)
#pragma unroll
        for (int i = 0; i < 4; ++i) {
            float v = c2[t][i] + b2v[t];
            if (RELU2) v = fmaxf(v, 0.f);
            L[(4 * g + i) * S2 + t * 16 + r] = (short)f2b(v);
        }
    asm volatile("" ::: "memory");
    if (TOHT) {
        int node0 = tile * 2;
#pragma unroll
        for (int half = 0; half < 2; ++half) {
            bf16x8 v;
#pragma unroll
            for (int c = 0; c < 8; ++c) v[c] = L[(half * 8 + c) * S2 + lane];
            *(bf16x8*)(hout + (size_t)(node0 + half) * 512 + lane * 8) = v;
        }
    } else {
        bf16x8 o0 = *(const bf16x8*)(L + r * S2 + 8 * g);
        *(bf16x8*)(hout + (size_t)(row0 + r) * OUT + 8 * g) = o0;
    }
}

// ---------------- rho: pool channels + 2-GEMM MLP, fp32 out ----------------
__global__ __launch_bounds__(256) void k_rho(
    const unsigned short* __restrict__ h2,
    const unsigned short* __restrict__ Wr1b, const float* __restrict__ br1,
    const unsigned short* __restrict__ Wr2b, const float* __restrict__ br2,
    float* __restrict__ out)
{
    constexpr int S = 72;
    __shared__ short lds[4][16 * S];
    int lane = threadIdx.x & 63, wid = threadIdx.x >> 6, g = lane >> 4, r = lane & 15;
    short* L = lds[wid];
    int tile = blockIdx.x * 4 + wid;      // 1250 tiles
    if (tile * 16 >= NN) return;
    bf16x8 w1f[4], w2f[2][4];
#pragma unroll
    for (int t = 0; t < 4; ++t) w1f[t] = load_bfrag(Wr1b, 64, 0, t * 16, lane);
#pragma unroll
    for (int kk = 0; kk < 2; ++kk)
#pragma unroll
        for (int t = 0; t < 4; ++t) w2f[kk][t] = load_bfrag(Wr2b, 64, kk * 32, t * 16, lane);
    float b1v[4], b2v[4];
#pragma unroll
    for (int t = 0; t < 4; ++t) { b1v[t] = br1[t * 16 + r]; b2v[t] = br2[t * 16 + r]; }

    int n = tile * 16 + r;
    float s[8] = {0.f, 0.f, 0.f, 0.f, 0.f, 0.f, 0.f, 0.f};
#pragma unroll
    for (int c = 0; c < NCH; ++c) {
        bf16x8 hv = *(const bf16x8*)(h2 + ((size_t)n * 8 + c) * 32 + 8 * g);
#pragma unroll
        for (int j = 0; j < 8; ++j) s[j] += b2f((unsigned short)hv[j]);
    }
    bf16x8 af;
#pragma unroll
    for (int j = 0; j < 8; ++j) af[j] = (short)f2b(s[j]);
    f32x4 c1[4];
#pragma unroll
    for (int t = 0; t < 4; ++t) {
        f32x4 c = {0.f, 0.f, 0.f, 0.f};
        c1[t] = mfma16(af, w1f[t], c);
    }
#pragma unroll
    for (int t = 0; t < 4; ++t)
#pragma unroll
        for (int i = 0; i < 4; ++i)
            L[(4 * g + i) * S + t * 16 + r] = (short)f2b(fmaxf(c1[t][i] + b1v[t], 0.f));
    asm volatile("" ::: "memory");
    bf16x8 t0 = *(const bf16x8*)(L + r * S + 8 * g);
    bf16x8 t1 = *(const bf16x8*)(L + r * S + 32 + 8 * g);
    f32x4 c2[4];
#pragma unroll
    for (int t = 0; t < 4; ++t) {
        f32x4 c = {0.f, 0.f, 0.f, 0.f};
        c = mfma16(t0, w2f[0][t], c);
        c = mfma16(t1, w2f[1][t], c);
        c2[t] = c;
    }
    int nb = tile * 16;
#pragma unroll
    for (int t = 0; t < 4; ++t)
#pragma unroll
        for (int i = 0; i < 4; ++i)
            out[(size_t)(nb + 4 * g + i) * 64 + t * 16 + r] = c2[t][i] + b2v[t];
}

extern "C" void kernel_launch(void* const* d_in, const int* in_sizes, int n_in,
                              void* d_out, int out_size, void* d_ws, size_t ws_size,
                              hipStream_t stream)
{
    const float* x   = (const float*)d_in[0];
    const float* ea  = (const float*)d_in[1];
    const int*   ei  = (const int*)d_in[2];
    const float* We0 = (const float*)d_in[3];
    const float* be0 = (const float*)d_in[4];
    const float* W10 = (const float*)d_in[5];
    const float* b10 = (const float*)d_in[6];
    const float* W20 = (const float*)d_in[7];
    const float* b20 = (const float*)d_in[8];
    const float* We1 = (const float*)d_in[9];
    const float* be1 = (const float*)d_in[10];
    const float* W11 = (const float*)d_in[11];
    const float* b11 = (const float*)d_in[12];
    const float* W21 = (const float*)d_in[13];
    const float* b21 = (const float*)d_in[14];
    const float* We2 = (const float*)d_in[15];
    const float* be2 = (const float*)d_in[16];
    const float* W12 = (const float*)d_in[17];
    const float* b12 = (const float*)d_in[18];
    const float* W22 = (const float*)d_in[19];
    const float* b22 = (const float*)d_in[20];
    const float* Wr1 = (const float*)d_in[21];
    const float* br1 = (const float*)d_in[22];
    const float* Wr2 = (const float*)d_in[23];
    const float* br2 = (const float*)d_in[24];
    float* out = (float*)d_out;

    // ---- workspace layout (128B-aligned blocks) ----
    char* base = (char*)d_ws;
    unsigned short* hT   = (unsigned short*)base; base += (size_t)NN * 512 * 2;        // 20.48 MB
    unsigned short* z    = (unsigned short*)base; base += (size_t)160000 * 64 * 2;     // 20.48 MB
    unsigned short* h2   = (unsigned short*)base; base += (size_t)160000 * 32 * 2;     // 10.24 MB
    unsigned short* eap  = (unsigned short*)base; base += (size_t)NE * 32 * 2;         // 40.96 MB
    float* emb0          = (float*)base;          base += (size_t)NE * 4;              //  2.56 MB
    float* z0            = (float*)base;          base += (size_t)160000 * 4;          //  0.64 MB
    float* xt            = (float*)base;          base += (size_t)NN * 4 * 4;          //  0.32 MB
    int2* se             = (int2*)base;           base += (size_t)NE * 8;              //  5.12 MB
    int* row             = (int*)base;            base += 80128;
    int* cnt             = (int*)base;            base += 80128;
    int* cursor          = (int*)base;            base += 80128;
    unsigned short* bw   = (unsigned short*)base;                                      // 57 KB

    const unsigned short* bWe1 = bw;
    const unsigned short* bWe2 = bw + 2048;
    const unsigned short* bW11 = bw + 4096;
    const unsigned short* bW21 = bw + 8192;
    const unsigned short* bW12 = bw + 12288;
    const unsigned short* bW22 = bw + 16384;
    const unsigned short* bW20 = bw + 18432;
    const unsigned short* bWr1 = bw + 22528;
    const unsigned short* bWr2 = bw + 24576;

    // ---- prep ----
    k_prep<<<112, 256, 0, stream>>>(We1, We2, W11, W21, W12, W22, W20, Wr1, Wr2, bw);
    hipMemsetAsync(cnt, 0, NN * sizeof(int), stream);
    k_hist<<<NE / 256, 256, 0, stream>>>(ei, cnt);
    k_scan<<<1, 512, 0, stream>>>(cnt, row, cursor);
    k_scatter<<<NE / 256, 256, 0, stream>>>(ei, cursor, se);
    k_permea<<<NE / 256, 256, 0, stream>>>(ea, se, We0, be0, eap, emb0);
    k_xt<<<(NN + 255) / 256, 256, 0, stream>>>(x, xt);

    // ---- layer 0 ----
    k_l0_gather<<<(NN * NCH) / 256, 256, 0, stream>>>(xt, se, row, emb0, z0);
    k_l0_mlp<<<2500, 256, 0, stream>>>(z0, W10, b10, bW20, b20, hT);

    // ---- layer 1 ----
    k_gather_f<<<NN / 4, 256, 0, stream>>>(se, row, eap, bWe1, be1, hT, z);
    k_mlp<64, true, true><<<2500, 256, 0, stream>>>(z, bW11, b11, bW21, b21, hT);

    // ---- layer 2 ----
    k_gather_f<<<NN / 4, 256, 0, stream>>>(se, row, eap, bWe2, be2, hT, z);
    k_mlp<32, false, false><<<2500, 256, 0, stream>>>(z, bW12, b12, bW22, b22, h2);

    // ---- pool + rho ----
    k_rho<<<313, 256, 0, stream>>>(h2, bWr1, br1, bWr2, br2, out);
}

// Round 5
// 404.884 us; speedup vs baseline: 7.4042x; 1.0379x over previous
//
#include <hip/hip_runtime.h>

#define NN 20000
#define NE 640000
#define NCH 8
#define HID 64
#define EDIM 32
#define ODIM 64

typedef __attribute__((ext_vector_type(8))) short bf16x8;
typedef __attribute__((ext_vector_type(4))) float f32x4;

__device__ __forceinline__ float b2f(unsigned short u) {
    unsigned v = ((unsigned)u) << 16;
    return __builtin_bit_cast(float, v);
}
__device__ __forceinline__ unsigned short f2b(float f) {   // RNE
    unsigned u = __builtin_bit_cast(unsigned, f);
    unsigned r = (u + 0x7fffu + ((u >> 16) & 1u)) >> 16;
    return (unsigned short)r;
}
__device__ __forceinline__ f32x4 mfma16(bf16x8 a, bf16x8 b, f32x4 c) {
    return __builtin_amdgcn_mfma_f32_16x16x32_bf16(a, b, c, 0, 0, 0);
}
// B-fragment: lane(g=l>>4, r=l&15) holds B[k0+8g+j][n0+r], W row-major [K][ldn]
__device__ __forceinline__ bf16x8 load_bfrag(const unsigned short* W, int ldn, int k0, int n0, int lane) {
    int g = lane >> 4, r = lane & 15;
    bf16x8 f;
#pragma unroll
    for (int j = 0; j < 8; ++j) f[j] = (short)W[(k0 + 8 * g + j) * ldn + n0 + r];
    return f;
}

// ---------------- weight cast fp32 -> bf16 (one shot) ----------------
__global__ __launch_bounds__(256) void k_prep(
    const float* We1, const float* We2, const float* W11, const float* W21,
    const float* W12, const float* W22, const float* W20, const float* Wr1,
    const float* Wr2, unsigned short* bw)
{
    int gid = blockIdx.x * 256 + threadIdx.x;
    const float* src; int off;
    if      (gid < 2048)  { src = We1; off = 0; }
    else if (gid < 4096)  { src = We2; off = 2048; }
    else if (gid < 8192)  { src = W11; off = 4096; }
    else if (gid < 12288) { src = W21; off = 8192; }
    else if (gid < 16384) { src = W12; off = 12288; }
    else if (gid < 18432) { src = W22; off = 16384; }
    else if (gid < 22528) { src = W20; off = 18432; }
    else if (gid < 24576) { src = Wr1; off = 22528; }
    else                  { src = Wr2; off = 24576; }
    bw[gid] = f2b(src[gid - off]);
}

// ---------------- CSR build ----------------
__global__ __launch_bounds__(256) void k_hist(const int* __restrict__ ei, int* __restrict__ cnt)
{
    int e = blockIdx.x * 256 + threadIdx.x;
    if (e < NE) atomicAdd(&cnt[ei[NE + e]], 1);
}

__global__ __launch_bounds__(512) void k_scan(const int* __restrict__ cnt,
                                              int* __restrict__ row, int* __restrict__ cursor)
{
    __shared__ int part[512];
    int t = threadIdx.x;
    int base = t * 40;
    int s = 0;
#pragma unroll
    for (int i = 0; i < 40; ++i) { int idx = base + i; if (idx < NN) s += cnt[idx]; }
    part[t] = s;
    __syncthreads();
    int v = s;
    for (int off = 1; off < 512; off <<= 1) {
        int add = (t >= off) ? part[t - off] : 0;
        __syncthreads();
        v += add;
        part[t] = v;
        __syncthreads();
    }
    int run = v - s;
    for (int i = 0; i < 40; ++i) {
        int idx = base + i;
        if (idx < NN) { row[idx] = run; cursor[idx] = run; run += cnt[idx]; }
    }
    if (t == 511) row[NN] = NE;
}

__global__ __launch_bounds__(256) void k_scatter(const int* __restrict__ ei,
                                                 int* __restrict__ cursor,
                                                 int* __restrict__ srcp, int* __restrict__ eidp)
{
    int e = blockIdx.x * 256 + threadIdx.x;
    if (e < NE) {
        int d = ei[NE + e];
        int pos = atomicAdd(&cursor[d], 1);
        srcp[pos] = ei[e];
        eidp[pos] = e;
    }
}

// ---------------- permute ea into CSR order (bf16) + layer-0 scalar embed ----------------
__global__ __launch_bounds__(256) void k_permea(
    const float* __restrict__ ea, const int* __restrict__ eidp,
    const float* __restrict__ We0, const float* __restrict__ be0,
    unsigned short* __restrict__ eap, float* __restrict__ emb0)
{
    int p = blockIdx.x * 256 + threadIdx.x;
    if (p >= NE) return;
    int eid = eidp[p];
    const f32x4* s4 = (const f32x4*)(ea + (size_t)eid * 32);
    float e0 = be0[0];
#pragma unroll
    for (int h = 0; h < 4; ++h) {
        f32x4 a = s4[2 * h], b = s4[2 * h + 1];
        bf16x8 o;
#pragma unroll
        for (int j = 0; j < 4; ++j) {
            e0 = fmaf(a[j], We0[h * 8 + j], e0);
            e0 = fmaf(b[j], We0[h * 8 + 4 + j], e0);
            o[j] = (short)f2b(a[j]);
            o[4 + j] = (short)f2b(b[j]);
        }
        *(bf16x8*)(eap + (size_t)p * 32 + h * 8) = o;
    }
    emb0[p] = e0;
}

// ---------------- x transpose: xt[node][4] ----------------
__global__ __launch_bounds__(256) void k_xt(const float* __restrict__ x, float* __restrict__ xt)
{
    int n = blockIdx.x * 256 + threadIdx.x;
    if (n < NN) {
        f32x4 v = {x[n], x[NN + n], x[2 * NN + n], x[3 * NN + n]};
        *(f32x4*)(xt + (size_t)n * 4) = v;
    }
}

// ---------------- layer-0 gather: thread per (node, k), both signs ----------------
__global__ __launch_bounds__(256) void k_l0_gather(
    const float* __restrict__ xt, const int* __restrict__ srcp,
    const int* __restrict__ row, const float* __restrict__ emb0,
    float* __restrict__ z0)
{
    int gid = blockIdx.x * 256 + threadIdx.x;
    if (gid >= NN * 4) return;
    int d = gid >> 2, k = gid & 3;
    float accp = 0.f, accm = 0.f;
    int p1 = row[d + 1];
    for (int p = row[d]; p < p1; ++p) {
        float xs = xt[(size_t)srcp[p] * 4 + k];
        float e0 = emb0[p];
        accp += fmaxf(xs + e0, 0.f);
        accm += fmaxf(e0 - xs, 0.f);
    }
    float xd = xt[(size_t)d * 4 + k];
    z0[d * 8 + k] = xd + accp;
    z0[d * 8 + k + 4] = accm - xd;
}

// ---------------- layer-0 MLP -> hT [node][feat][ch] ----------------
__global__ __launch_bounds__(256) void k_l0_mlp(
    const float* __restrict__ z0,
    const float* __restrict__ W1, const float* __restrict__ b1,
    const unsigned short* __restrict__ W2b, const float* __restrict__ b2,
    unsigned short* __restrict__ hT)
{
    constexpr int S = 72;
    __shared__ short lds[4][16 * S];
    int lane = threadIdx.x & 63, wid = threadIdx.x >> 6, g = lane >> 4, r = lane & 15;
    short* L = lds[wid];
    bf16x8 w2f[2][4];
#pragma unroll
    for (int kk = 0; kk < 2; ++kk)
#pragma unroll
        for (int t = 0; t < 4; ++t) w2f[kk][t] = load_bfrag(W2b, 64, kk * 32, t * 16, lane);
    float b2v[4];
#pragma unroll
    for (int t = 0; t < 4; ++t) b2v[t] = b2[t * 16 + r];
    float w1a[8], w1b[8], b1a[8], b1b[8];
#pragma unroll
    for (int j = 0; j < 8; ++j) {
        w1a[j] = W1[8 * g + j];      b1a[j] = b1[8 * g + j];
        w1b[j] = W1[32 + 8 * g + j]; b1b[j] = b1[32 + 8 * g + j];
    }
    int tile = blockIdx.x * 4 + wid;      // 10000 tiles
    int row0 = tile * 16;
    float zv = z0[row0 + r];
    bf16x8 a0, a1;
#pragma unroll
    for (int j = 0; j < 8; ++j) {
        a0[j] = (short)f2b(fmaxf(fmaf(zv, w1a[j], b1a[j]), 0.f));
        a1[j] = (short)f2b(fmaxf(fmaf(zv, w1b[j], b1b[j]), 0.f));
    }
    f32x4 c2[4];
#pragma unroll
    for (int t = 0; t < 4; ++t) {
        f32x4 c = {0.f, 0.f, 0.f, 0.f};
        c = mfma16(a0, w2f[0][t], c);
        c = mfma16(a1, w2f[1][t], c);
        c2[t] = c;
    }
#pragma unroll
    for (int t = 0; t < 4; ++t)
#pragma unroll
        for (int i = 0; i < 4; ++i)
            L[(4 * g + i) * S + t * 16 + r] = (short)f2b(fmaxf(c2[t][i] + b2v[t], 0.f));
    asm volatile("" ::: "memory");
    int node0 = tile * 2;
#pragma unroll
    for (int half = 0; half < 2; ++half) {
        bf16x8 v;
#pragma unroll
        for (int c = 0; c < 8; ++c) v[c] = L[(half * 8 + c) * S + lane];
        *(bf16x8*)(hT + (size_t)(node0 + half) * 512 + lane * 8) = v;
    }
}

// ---------------- fused gather: emb MFMA in-wave + unrolled h-row gather ----------------
__global__ __launch_bounds__(256) void k_gather_f(
    const int* __restrict__ srcp, const int* __restrict__ row,
    const unsigned short* __restrict__ eap,
    const unsigned short* __restrict__ Web, const float* __restrict__ be,
    const unsigned short* __restrict__ hT, unsigned short* __restrict__ z)
{
    constexpr int S4 = 66;
    __shared__ float lds[4][16 * S4];
    int lane = threadIdx.x & 63, wid = threadIdx.x >> 6, g = lane >> 4, r = lane & 15;
    float* L = lds[wid];
    bf16x8 wf[4];
#pragma unroll
    for (int t = 0; t < 4; ++t) wf[t] = load_bfrag(Web, 64, 0, t * 16, lane);
    float bev[4];
#pragma unroll
    for (int t = 0; t < 4; ++t) bev[t] = be[t * 16 + r];

    int d = blockIdx.x * 4 + wid;     // 5000 blocks x 4 waves = 20000
    int p0 = row[d], p1 = row[d + 1];
    float acc[NCH];
#pragma unroll
    for (int c = 0; c < NCH; ++c) acc[c] = 0.f;

    // preload first tile (A-fragment + src vector)
    bf16x8 afc = {0,0,0,0,0,0,0,0};
    int svc = 0;
    if (p0 < p1) {
        int pp = p0 + r; if (pp > p1 - 1) pp = p1 - 1;
        afc = *(const bf16x8*)(eap + (size_t)pp * 32 + 8 * g);
        svc = srcp[pp];
    }

    for (int p = p0; p < p1; p += 16) {
        int ne = p1 - p; if (ne > 16) ne = 16;
        // emb tile MFMA (bias folded into C-init)
        f32x4 c[4];
#pragma unroll
        for (int t = 0; t < 4; ++t) {
            f32x4 cc = {bev[t], bev[t], bev[t], bev[t]};
            c[t] = mfma16(afc, wf[t], cc);
        }
        // prefetch next tile
        bf16x8 afn = afc; int svn = svc;
        int pn = p + 16;
        if (pn < p1) {
            int ppn = pn + r; if (ppn > p1 - 1) ppn = p1 - 1;
            afn = *(const bf16x8*)(eap + (size_t)ppn * 32 + 8 * g);
            svn = srcp[ppn];
        }
        // write emb tile to LDS (fp32), poison rows >= ne with -inf
#pragma unroll
        for (int t = 0; t < 4; ++t)
#pragma unroll
            for (int i = 0; i < 4; ++i) {
                float v = (4 * g + i < ne) ? c[t][i] : -__builtin_inff();
                L[(4 * g + i) * S4 + t * 16 + r] = v;
            }
        asm volatile("" ::: "memory");
        // fully-unrolled 16-edge accumulate (invalid edges contribute 0 via -inf)
#pragma unroll
        for (int q = 0; q < 16; ++q) {
            int src = __builtin_amdgcn_readlane(svc, q);
            float em = L[q * S4 + lane];
            uint4 hv = *(const uint4*)(hT + (size_t)src * 512 + (lane << 3));
            unsigned dw0 = hv.x, dw1 = hv.y, dw2 = hv.z, dw3 = hv.w;
            acc[0] += fmaxf(__builtin_bit_cast(float, dw0 << 16) + em, 0.f);
            acc[1] += fmaxf(__builtin_bit_cast(float, dw0 & 0xffff0000u) + em, 0.f);
            acc[2] += fmaxf(__builtin_bit_cast(float, dw1 << 16) + em, 0.f);
            acc[3] += fmaxf(__builtin_bit_cast(float, dw1 & 0xffff0000u) + em, 0.f);
            acc[4] += fmaxf(__builtin_bit_cast(float, dw2 << 16) + em, 0.f);
            acc[5] += fmaxf(__builtin_bit_cast(float, dw2 & 0xffff0000u) + em, 0.f);
            acc[6] += fmaxf(__builtin_bit_cast(float, dw3 << 16) + em, 0.f);
            acc[7] += fmaxf(__builtin_bit_cast(float, dw3 & 0xffff0000u) + em, 0.f);
        }
        asm volatile("" ::: "memory");
        afc = afn; svc = svn;
    }

    // epilogue: z = h_dst + acc
    uint4 hd = *(const uint4*)(hT + (size_t)d * 512 + (lane << 3));
    unsigned hw[4] = {hd.x, hd.y, hd.z, hd.w};
    unsigned short* zd = z + (size_t)d * 8 * 64 + lane;
#pragma unroll
    for (int j = 0; j < 4; ++j) {
        float lo = __builtin_bit_cast(float, hw[j] << 16);
        float hi = __builtin_bit_cast(float, hw[j] & 0xffff0000u);
        zd[(2 * j) * 64] = f2b(lo + acc[2 * j]);
        zd[(2 * j + 1) * 64] = f2b(hi + acc[2 * j + 1]);
    }
}

// ---------------- node MLP: z -> (hT | h2-rows) ----------------
template <int OUT, bool RELU2, bool TOHT>
__global__ __launch_bounds__(256) void k_mlp(
    const unsigned short* __restrict__ z,
    const unsigned short* __restrict__ W1b, const float* __restrict__ b1,
    const unsigned short* __restrict__ W2b, const float* __restrict__ b2,
    unsigned short* __restrict__ hout)
{
    constexpr int S1 = 72;
    constexpr int S2 = (OUT == 64) ? 72 : 40;
    constexpr int NT2 = OUT / 16;
    __shared__ short lds[4][16 * S1];
    int lane = threadIdx.x & 63, wid = threadIdx.x >> 6, g = lane >> 4, r = lane & 15;
    short* L = lds[wid];

    bf16x8 w1f[2][4];
#pragma unroll
    for (int kk = 0; kk < 2; ++kk)
#pragma unroll
        for (int t = 0; t < 4; ++t) w1f[kk][t] = load_bfrag(W1b, 64, kk * 32, t * 16, lane);
    bf16x8 w2f[2][NT2];
#pragma unroll
    for (int kk = 0; kk < 2; ++kk)
#pragma unroll
        for (int t = 0; t < NT2; ++t) w2f[kk][t] = load_bfrag(W2b, OUT, kk * 32, t * 16, lane);
    float b1v[4], b2v[NT2];
#pragma unroll
    for (int t = 0; t < 4; ++t) b1v[t] = b1[t * 16 + r];
#pragma unroll
    for (int t = 0; t < NT2; ++t) b2v[t] = b2[t * 16 + r];

    int tile = blockIdx.x * 4 + wid;      // 10000 tiles
    int row0 = tile * 16;

    bf16x8 a0 = *(const bf16x8*)(z + (size_t)(row0 + r) * 64 + 8 * g);
    bf16x8 a1 = *(const bf16x8*)(z + (size_t)(row0 + r) * 64 + 32 + 8 * g);
    f32x4 c1[4];
#pragma unroll
    for (int t = 0; t < 4; ++t) {
        f32x4 c = {0.f, 0.f, 0.f, 0.f};
        c = mfma16(a0, w1f[0][t], c);
        c = mfma16(a1, w1f[1][t], c);
        c1[t] = c;
    }
#pragma unroll
    for (int t = 0; t < 4; ++t)
#pragma unroll
        for (int i = 0; i < 4; ++i)
            L[(4 * g + i) * S1 + t * 16 + r] = (short)f2b(fmaxf(c1[t][i] + b1v[t], 0.f));
    asm volatile("" ::: "memory");
    bf16x8 t0 = *(const bf16x8*)(L + r * S1 + 8 * g);
    bf16x8 t1 = *(const bf16x8*)(L + r * S1 + 32 + 8 * g);
    f32x4 c2[NT2];
#pragma unroll
    for (int t = 0; t < NT2; ++t) {
        f32x4 c = {0.f, 0.f, 0.f, 0.f};
        c = mfma16(t0, w2f[0][t], c);
        c = mfma16(t1, w2f[1][t], c);
        c2[t] = c;
    }
    asm volatile("" ::: "memory");
#pragma unroll
    for (int t = 0; t < NT2; ++t)
#pragma unroll
        for (int i = 0; i < 4; ++i) {
            float v = c2[t][i] + b2v[t];
            if (RELU2) v = fmaxf(v, 0.f);
            L[(4 * g + i) * S2 + t * 16 + r] = (short)f2b(v);
        }
    asm volatile("" ::: "memory");
    if (TOHT) {
        int node0 = tile * 2;
#pragma unroll
        for (int half = 0; half < 2; ++half) {
            bf16x8 v;
#pragma unroll
            for (int c = 0; c < 8; ++c) v[c] = L[(half * 8 + c) * S2 + lane];
            *(bf16x8*)(hout + (size_t)(node0 + half) * 512 + lane * 8) = v;
        }
    } else {
        bf16x8 o0 = *(const bf16x8*)(L + r * S2 + 8 * g);
        *(bf16x8*)(hout + (size_t)(row0 + r) * OUT + 8 * g) = o0;
    }
}

// ---------------- rho: pool channels + 2-GEMM MLP, fp32 out ----------------
__global__ __launch_bounds__(256) void k_rho(
    const unsigned short* __restrict__ h2,
    const unsigned short* __restrict__ Wr1b, const float* __restrict__ br1,
    const unsigned short* __restrict__ Wr2b, const float* __restrict__ br2,
    float* __restrict__ out)
{
    constexpr int S = 72;
    __shared__ short lds[4][16 * S];
    int lane = threadIdx.x & 63, wid = threadIdx.x >> 6, g = lane >> 4, r = lane & 15;
    short* L = lds[wid];
    int tile = blockIdx.x * 4 + wid;      // 1250 tiles
    if (tile * 16 >= NN) return;
    bf16x8 w1f[4], w2f[2][4];
#pragma unroll
    for (int t = 0; t < 4; ++t) w1f[t] = load_bfrag(Wr1b, 64, 0, t * 16, lane);
#pragma unroll
    for (int kk = 0; kk < 2; ++kk)
#pragma unroll
        for (int t = 0; t < 4; ++t) w2f[kk][t] = load_bfrag(Wr2b, 64, kk * 32, t * 16, lane);
    float b1v[4], b2v[4];
#pragma unroll
    for (int t = 0; t < 4; ++t) { b1v[t] = br1[t * 16 + r]; b2v[t] = br2[t * 16 + r]; }

    int n = tile * 16 + r;
    float s[8] = {0.f, 0.f, 0.f, 0.f, 0.f, 0.f, 0.f, 0.f};
#pragma unroll
    for (int c = 0; c < NCH; ++c) {
        bf16x8 hv = *(const bf16x8*)(h2 + ((size_t)n * 8 + c) * 32 + 8 * g);
#pragma unroll
        for (int j = 0; j < 8; ++j) s[j] += b2f((unsigned short)hv[j]);
    }
    bf16x8 af;
#pragma unroll
    for (int j = 0; j < 8; ++j) af[j] = (short)f2b(s[j]);
    f32x4 c1[4];
#pragma unroll
    for (int t = 0; t < 4; ++t) {
        f32x4 c = {0.f, 0.f, 0.f, 0.f};
        c1[t] = mfma16(af, w1f[t], c);
    }
#pragma unroll
    for (int t = 0; t < 4; ++t)
#pragma unroll
        for (int i = 0; i < 4; ++i)
            L[(4 * g + i) * S + t * 16 + r] = (short)f2b(fmaxf(c1[t][i] + b1v[t], 0.f));
    asm volatile("" ::: "memory");
    bf16x8 t0 = *(const bf16x8*)(L + r * S + 8 * g);
    bf16x8 t1 = *(const bf16x8*)(L + r * S + 32 + 8 * g);
    f32x4 c2[4];
#pragma unroll
    for (int t = 0; t < 4; ++t) {
        f32x4 c = {0.f, 0.f, 0.f, 0.f};
        c = mfma16(t0, w2f[0][t], c);
        c = mfma16(t1, w2f[1][t], c);
        c2[t] = c;
    }
    int nb = tile * 16;
#pragma unroll
    for (int t = 0; t < 4; ++t)
#pragma unroll
        for (int i = 0; i < 4; ++i)
            out[(size_t)(nb + 4 * g + i) * 64 + t * 16 + r] = c2[t][i] + b2v[t];
}

extern "C" void kernel_launch(void* const* d_in, const int* in_sizes, int n_in,
                              void* d_out, int out_size, void* d_ws, size_t ws_size,
                              hipStream_t stream)
{
    const float* x   = (const float*)d_in[0];
    const float* ea  = (const float*)d_in[1];
    const int*   ei  = (const int*)d_in[2];
    const float* We0 = (const float*)d_in[3];
    const float* be0 = (const float*)d_in[4];
    const float* W10 = (const float*)d_in[5];
    const float* b10 = (const float*)d_in[6];
    const float* W20 = (const float*)d_in[7];
    const float* b20 = (const float*)d_in[8];
    const float* We1 = (const float*)d_in[9];
    const float* be1 = (const float*)d_in[10];
    const float* W11 = (const float*)d_in[11];
    const float* b11 = (const float*)d_in[12];
    const float* W21 = (const float*)d_in[13];
    const float* b21 = (const float*)d_in[14];
    const float* We2 = (const float*)d_in[15];
    const float* be2 = (const float*)d_in[16];
    const float* W12 = (const float*)d_in[17];
    const float* b12 = (const float*)d_in[18];
    const float* W22 = (const float*)d_in[19];
    const float* b22 = (const float*)d_in[20];
    const float* Wr1 = (const float*)d_in[21];
    const float* br1 = (const float*)d_in[22];
    const float* Wr2 = (const float*)d_in[23];
    const float* br2 = (const float*)d_in[24];
    float* out = (float*)d_out;

    // ---- workspace layout (128B-aligned blocks) ----
    char* base = (char*)d_ws;
    unsigned short* hT   = (unsigned short*)base; base += (size_t)NN * 512 * 2;        // 20.48 MB
    unsigned short* z    = (unsigned short*)base; base += (size_t)160000 * 64 * 2;     // 20.48 MB
    unsigned short* h2   = (unsigned short*)base; base += (size_t)160000 * 32 * 2;     // 10.24 MB
    unsigned short* eap  = (unsigned short*)base; base += (size_t)NE * 32 * 2;         // 40.96 MB
    float* emb0          = (float*)base;          base += (size_t)NE * 4;              //  2.56 MB
    float* z0            = (float*)base;          base += (size_t)160000 * 4;          //  0.64 MB
    float* xt            = (float*)base;          base += (size_t)NN * 4 * 4;          //  0.32 MB
    int* srcp            = (int*)base;            base += (size_t)NE * 4;              //  2.56 MB
    int* eidp            = (int*)base;            base += (size_t)NE * 4;              //  2.56 MB
    int* row             = (int*)base;            base += 80128;
    int* cnt             = (int*)base;            base += 80128;
    int* cursor          = (int*)base;            base += 80128;
    unsigned short* bw   = (unsigned short*)base;                                      // 57 KB

    const unsigned short* bWe1 = bw;
    const unsigned short* bWe2 = bw + 2048;
    const unsigned short* bW11 = bw + 4096;
    const unsigned short* bW21 = bw + 8192;
    const unsigned short* bW12 = bw + 12288;
    const unsigned short* bW22 = bw + 16384;
    const unsigned short* bW20 = bw + 18432;
    const unsigned short* bWr1 = bw + 22528;
    const unsigned short* bWr2 = bw + 24576;

    // ---- prep ----
    k_prep<<<112, 256, 0, stream>>>(We1, We2, W11, W21, W12, W22, W20, Wr1, Wr2, bw);
    hipMemsetAsync(cnt, 0, NN * sizeof(int), stream);
    k_hist<<<NE / 256, 256, 0, stream>>>(ei, cnt);
    k_scan<<<1, 512, 0, stream>>>(cnt, row, cursor);
    k_scatter<<<NE / 256, 256, 0, stream>>>(ei, cursor, srcp, eidp);
    k_permea<<<NE / 256, 256, 0, stream>>>(ea, eidp, We0, be0, eap, emb0);
    k_xt<<<(NN + 255) / 256, 256, 0, stream>>>(x, xt);

    // ---- layer 0 ----
    k_l0_gather<<<(NN * 4 + 255) / 256, 256, 0, stream>>>(xt, srcp, row, emb0, z0);
    k_l0_mlp<<<2500, 256, 0, stream>>>(z0, W10, b10, bW20, b20, hT);

    // ---- layer 1 ----
    k_gather_f<<<NN / 4, 256, 0, stream>>>(srcp, row, eap, bWe1, be1, hT, z);
    k_mlp<64, true, true><<<2500, 256, 0, stream>>>(z, bW11, b11, bW21, b21, hT);

    // ---- layer 2 ----
    k_gather_f<<<NN / 4, 256, 0, stream>>>(srcp, row, eap, bWe2, be2, hT, z);
    k_mlp<32, false, false><<<2500, 256, 0, stream>>>(z, bW12, b12, bW22, b22, h2);

    // ---- pool + rho ----
    k_rho<<<313, 256, 0, stream>>>(h2, bWr1, br1, bWr2, br2, out);
}